// Round 2
// baseline (4085.032 us; speedup 1.0000x reference)
//
#include <hip/hip_runtime.h>

#define BATCH 32
#define HGRID 24
#define WGRID 24
#define DIN   768
#define HID   384
#define GATES 1536
#define SEQT  24
#define NROWS (BATCH*HGRID*WGRID)   /* 18432 feature rows */
#define NSEQ  (BATCH*HGRID)         /* 768 sequences per direction-set */
#define SCH   6                     /* sequences per recurrence block */

struct WPtrs {
  const float* Wx[4];
  const float* Wh[4];
  const float* b[4];
};

__device__ __forceinline__ float fast_sigmoid(float x) {
  x = fminf(fmaxf(x, -30.f), 30.f);
  float e = __builtin_amdgcn_exp2f(-1.44269504f * x);
  return __builtin_amdgcn_rcpf(1.0f + e);
}
__device__ __forceinline__ float fast_tanh(float x) {
  x = fminf(fmaxf(x, -15.f), 15.f);
  float e = __builtin_amdgcn_exp2f(-2.88539008f * x);   /* e^(-2x) */
  return (1.0f - e) * __builtin_amdgcn_rcpf(1.0f + e);
}

/* bf16 round-to-nearest-even pack: low16 = bf16(a), high16 = bf16(b).
 * unpack: a = asfloat(p<<16), b = asfloat(p & 0xFFFF0000). */
__device__ __forceinline__ unsigned bpack(float a, float b) {
  unsigned ua = __float_as_uint(a);
  ua = (ua + 0x7FFFu + ((ua >> 16) & 1u)) >> 16;
  unsigned ub = __float_as_uint(b);
  ub = (ub + 0x7FFFu + ((ub >> 16) & 1u)) & 0xFFFF0000u;
  return ua | ub;
}

/* ---------------- Phase 0: repack Wh -> bf16x4 per (k,q) -------------------
 * Wh2[l][k][q] = uint2{ pack(wi,wf), pack(wc,wo) } where wi=Wh[k][q],
 * wf=Wh[k][384+q], wc=Wh[k][768+q], wo=Wh[k][1152+q].
 * Turns recur's 4 strided scalar loads/k into 1 coalesced dwordx2, and
 * halves per-step L2 Wh traffic. */
__global__ __launch_bounds__(256) void repack_wh(WPtrs P, uint2* __restrict__ Wh2) {
  const int idx = blockIdx.x * 256 + threadIdx.x;
  if (idx >= 4 * HID * HID) return;
  const int l = idx / (HID * HID);
  const int r = idx % (HID * HID);
  const int k = r / HID;
  const int q = r % HID;
  const float* row = P.Wh[l] + (size_t)k * GATES;
  uint2 o;
  o.x = bpack(row[q], row[384 + q]);
  o.y = bpack(row[768 + q], row[1152 + q]);
  Wh2[(size_t)l * HID * HID + (size_t)k * HID + q] = o;
}

/* ---------------- Phase 1: Z[l][r][g] = X[r][:] @ Wx_l + b_l ----------------
 * (unchanged from R1 — 69% of fp32 peak; MFMA rewrite is a later round) */
__global__ __launch_bounds__(256) void gemm_z(const float* __restrict__ X,
                                              WPtrs P, int lbase,
                                              float* __restrict__ Z) {
  const int bx = blockIdx.x;
  const int l_local = bx / 24;
  const int n0 = (bx % 24) * 64;
  const int m0 = blockIdx.y * 128;
  const float* __restrict__ Wx   = P.Wx[lbase + l_local];
  const float* __restrict__ bias = P.b[lbase + l_local];
  float* __restrict__ Zl = Z + (size_t)l_local * NROWS * GATES;

  __shared__ float As[16][128];   /* [k][m] */
  __shared__ float Bs[16][64];    /* [k][n] */

  const int tid = threadIdx.x;
  const int tx = tid & 15;
  const int ty = tid >> 4;

  float acc[8][4];
#pragma unroll
  for (int i = 0; i < 8; ++i)
#pragma unroll
    for (int j = 0; j < 4; ++j) acc[i][j] = 0.f;

  const int ar = tid >> 1;
  const int ak = (tid & 1) * 8;
  const float* Aptr = X + (size_t)(m0 + ar) * DIN + ak;
  const int bk = tid >> 4;
  const int bc = (tid & 15) * 4;
  const float* Bptr = Wx + (size_t)bk * GATES + n0 + bc;

  for (int k0 = 0; k0 < DIN; k0 += 16) {
    const float4 a0 = *(const float4*)(Aptr);
    const float4 a1 = *(const float4*)(Aptr + 4);
    const float4 bv = *(const float4*)(Bptr);
    Aptr += 16;
    Bptr += (size_t)16 * GATES;

    __syncthreads();
    As[ak + 0][ar] = a0.x; As[ak + 1][ar] = a0.y;
    As[ak + 2][ar] = a0.z; As[ak + 3][ar] = a0.w;
    As[ak + 4][ar] = a1.x; As[ak + 5][ar] = a1.y;
    As[ak + 6][ar] = a1.z; As[ak + 7][ar] = a1.w;
    *(float4*)&Bs[bk][bc] = bv;
    __syncthreads();

#pragma unroll
    for (int k = 0; k < 16; ++k) {
      const float4 av0 = *(const float4*)&As[k][ty * 8];
      const float4 av1 = *(const float4*)&As[k][ty * 8 + 4];
      const float4 bvv = *(const float4*)&Bs[k][tx * 4];
      const float ar8[8] = {av0.x, av0.y, av0.z, av0.w,
                            av1.x, av1.y, av1.z, av1.w};
      const float br4[4] = {bvv.x, bvv.y, bvv.z, bvv.w};
#pragma unroll
      for (int i = 0; i < 8; ++i)
#pragma unroll
        for (int j = 0; j < 4; ++j)
          acc[i][j] = fmaf(ar8[i], br4[j], acc[i][j]);
    }
  }

  float bs[4];
#pragma unroll
  for (int j = 0; j < 4; ++j) bs[j] = bias[n0 + tx * 4 + j];
#pragma unroll
  for (int i = 0; i < 8; ++i) {
    const int row = m0 + ty * 8 + i;
    float4 o;
    o.x = acc[i][0] + bs[0];
    o.y = acc[i][1] + bs[1];
    o.z = acc[i][2] + bs[2];
    o.w = acc[i][3] + bs[3];
    *(float4*)&Zl[(size_t)row * GATES + n0 + tx * 4] = o;
  }
}

/* ---------------- Phase 2: recurrence --------------------------------------
 * One block = one LSTM l x 6 sequences. 512 blocks -> 2 blocks/CU,
 * 12 waves/CU (3/SIMD balanced). Thread q owns hidden unit q; its 4 gate
 * weights arrive as one coalesced dwordx2 of packed bf16 (repack_wh).
 * h double-buffered in LDS -> one barrier/step. c in registers. */
__global__ __launch_bounds__(384, 3) void recur(const float* __restrict__ Z,
                                                float* __restrict__ out,
                                                const uint2* __restrict__ Wh2,
                                                int lbase, int group) {
  const int bi = blockIdx.x;
  const int l_local = bi % group;       /* round-robin -> XCD L2 locality */
  const int chunk = bi / group;
  const int l = lbase + l_local;
  const uint2* __restrict__ Whl = Wh2 + (size_t)l * HID * HID;
  const float* __restrict__ Zl = Z + (size_t)l_local * NROWS * GATES;
  const int q = threadIdx.x;            /* hidden unit 0..383 */
  const int n0 = chunk * SCH;
  const bool rev = (l & 1);

  __shared__ float h_lds[2][HID * 8];   /* [buf][k*8 + s], 2 x 12 KB */

  float c[SCH];
#pragma unroll
  for (int s = 0; s < SCH; ++s) c[s] = 0.f;
#pragma unroll
  for (int s = 0; s < 8; ++s) h_lds[0][q * 8 + s] = 0.f;
  __syncthreads();

  /* feature-row r(s,t): horizontal r = n*24 + t ; vertical r = (n/24)*576 + t*24 + n%24 */
  int rbase[SCH];
  int rstep;
  if (l < 2) {
    rstep = 1;
#pragma unroll
    for (int s = 0; s < SCH; ++s) rbase[s] = (n0 + s) * SEQT;
  } else {
    rstep = 24;
#pragma unroll
    for (int s = 0; s < SCH; ++s) {
      const int n = n0 + s;
      rbase[s] = (n / 24) * 576 + (n % 24);
    }
  }

  int cur = 0;
  for (int it = 0; it < SEQT; ++it) {
    const int tt = rev ? (SEQT - 1 - it) : it;

    float gi[SCH], gf[SCH], gc[SCH], go[SCH];
#pragma unroll
    for (int s = 0; s < SCH; ++s) {
      const float* zrow = Zl + (size_t)(rbase[s] + tt * rstep) * GATES;
      gi[s] = zrow[q];
      gf[s] = zrow[384 + q];
      gc[s] = zrow[768 + q];
      go[s] = zrow[1152 + q];
    }

    const uint2* wp = Whl + q;
    const float* hb = h_lds[cur];
#pragma unroll 8
    for (int k = 0; k < HID; ++k) {
      const uint2 w = wp[(size_t)k * HID];
      const float wi = __uint_as_float(w.x << 16);
      const float wf = __uint_as_float(w.x & 0xFFFF0000u);
      const float wc = __uint_as_float(w.y << 16);
      const float wo = __uint_as_float(w.y & 0xFFFF0000u);
      const float4 h0 = *(const float4*)&hb[k * 8];
      const float2 h1 = *(const float2*)&hb[k * 8 + 4];
      const float hv[SCH] = {h0.x, h0.y, h0.z, h0.w, h1.x, h1.y};
#pragma unroll
      for (int s = 0; s < SCH; ++s) {
        gi[s] = fmaf(hv[s], wi, gi[s]);
        gf[s] = fmaf(hv[s], wf, gf[s]);
        gc[s] = fmaf(hv[s], wc, gc[s]);
        go[s] = fmaf(hv[s], wo, go[s]);
      }
    }

    float* hn = h_lds[cur ^ 1];
#pragma unroll
    for (int s = 0; s < SCH; ++s) {
      const float ig = fast_sigmoid(gi[s]);
      const float fg = fast_sigmoid(gf[s]);
      const float cd = fast_tanh(gc[s]);
      const float og = fast_sigmoid(go[s]);
      const float cn = fmaf(fg, c[s], ig * cd);
      c[s] = cn;
      const float hv = og * fast_tanh(cn);
      hn[q * 8 + s] = hv;
      out[(size_t)(rbase[s] + tt * rstep) * GATES + l * HID + q] = hv;
    }
    __syncthreads();   /* new h visible before next step's GEMM reads */
    cur ^= 1;
  }
}

extern "C" void kernel_launch(void* const* d_in, const int* in_sizes, int n_in,
                              void* d_out, int out_size, void* d_ws, size_t ws_size,
                              hipStream_t stream) {
  const float* feat = (const float*)d_in[0];
  WPtrs P;
  P.Wx[0] = (const float*)d_in[1];  P.Wh[0] = (const float*)d_in[2];  P.b[0] = (const float*)d_in[3];
  P.Wx[1] = (const float*)d_in[4];  P.Wh[1] = (const float*)d_in[5];  P.b[1] = (const float*)d_in[6];
  P.Wx[2] = (const float*)d_in[7];  P.Wh[2] = (const float*)d_in[8];  P.b[2] = (const float*)d_in[9];
  P.Wx[3] = (const float*)d_in[10]; P.Wh[3] = (const float*)d_in[11]; P.b[3] = (const float*)d_in[12];
  float* out = (float*)d_out;
  float* Z = (float*)d_ws;

  const size_t slabB = (size_t)NROWS * GATES * sizeof(float);  /* 113.25 MB per LSTM */
  const size_t whB   = (size_t)4 * HID * HID * sizeof(uint2);  /* 4.72 MB packed Wh */
  const int group = (ws_size >= 4 * slabB + whB) ? 4
                  : (ws_size >= 2 * slabB + whB) ? 2 : 1;
  uint2* Wh2 = (uint2*)((char*)d_ws + (size_t)group * slabB);

  repack_wh<<<(4 * HID * HID + 255) / 256, 256, 0, stream>>>(P, Wh2);

  for (int lbase = 0; lbase < 4; lbase += group) {
    gemm_z<<<dim3(24 * group, NROWS / 128), 256, 0, stream>>>(feat, P, lbase, Z);
    recur<<<dim3((NSEQ / SCH) * group), 384, 0, stream>>>(Z, out, Wh2, lbase, group);
  }
}

// Round 3
// 3877.010 us; speedup vs baseline: 1.0537x; 1.0537x over previous
//
#include <hip/hip_runtime.h>

#define BATCH 32
#define HGRID 24
#define WGRID 24
#define DIN   768
#define HID   384
#define GATES 1536
#define SEQT  24
#define NROWS (BATCH*HGRID*WGRID)   /* 18432 feature rows */
#define NSEQ  (BATCH*HGRID)         /* 768 sequences per direction-set */
#define SCH   6                     /* sequences per recurrence block */

struct WPtrs {
  const float* Wx[4];
  const float* Wh[4];
  const float* b[4];
};

__device__ __forceinline__ float fast_sigmoid(float x) {
  x = fminf(fmaxf(x, -30.f), 30.f);
  float e = __builtin_amdgcn_exp2f(-1.44269504f * x);
  return __builtin_amdgcn_rcpf(1.0f + e);
}
__device__ __forceinline__ float fast_tanh(float x) {
  x = fminf(fmaxf(x, -15.f), 15.f);
  float e = __builtin_amdgcn_exp2f(-2.88539008f * x);   /* e^(-2x) */
  return (1.0f - e) * __builtin_amdgcn_rcpf(1.0f + e);
}

/* bf16 RNE helpers */
__device__ __forceinline__ unsigned short bfr(float a) {
  unsigned u = __float_as_uint(a);
  u = (u + 0x7FFFu + ((u >> 16) & 1u)) >> 16;
  return (unsigned short)u;
}
__device__ __forceinline__ unsigned bpack(float a, float b) {
  return (unsigned)bfr(a) | ((unsigned)bfr(b) << 16);
}
__device__ __forceinline__ float bup(unsigned short v) {
  return __uint_as_float(((unsigned)v) << 16);
}

/* ---------------- Phase 0: repack Wh -> bf16x4 per (k,q) -------------------
 * Wh2[l][k][q] = uint2{ pack(wi,wf), pack(wc,wo) }. One coalesced dwordx2
 * per k in recur instead of 4 strided scalar dwords. */
__global__ __launch_bounds__(256) void repack_wh(WPtrs P, uint2* __restrict__ Wh2) {
  const int idx = blockIdx.x * 256 + threadIdx.x;
  if (idx >= 4 * HID * HID) return;
  const int l = idx / (HID * HID);
  const int r = idx % (HID * HID);
  const int k = r / HID;
  const int q = r % HID;
  const float* row = P.Wh[l] + (size_t)k * GATES;
  uint2 o;
  o.x = bpack(row[q], row[384 + q]);
  o.y = bpack(row[768 + q], row[1152 + q]);
  Wh2[(size_t)l * HID * HID + (size_t)k * HID + q] = o;
}

/* ---------------- Phase 1: Z[l][r][g] = X[r][:] @ Wx_l + b_l ----------------
 * fp32 compute (69% of fp32 vector peak), bf16 output (halves Z footprint
 * so group=4 fits: ws_size is ~exactly 4 fp32 slabs). */
__global__ __launch_bounds__(256) void gemm_z(const float* __restrict__ X,
                                              WPtrs P, int lbase,
                                              unsigned short* __restrict__ Z) {
  const int bx = blockIdx.x;
  const int l_local = bx / 24;
  const int n0 = (bx % 24) * 64;
  const int m0 = blockIdx.y * 128;
  const float* __restrict__ Wx   = P.Wx[lbase + l_local];
  const float* __restrict__ bias = P.b[lbase + l_local];
  unsigned short* __restrict__ Zl = Z + (size_t)l_local * NROWS * GATES;

  __shared__ float As[16][128];   /* [k][m] */
  __shared__ float Bs[16][64];    /* [k][n] */

  const int tid = threadIdx.x;
  const int tx = tid & 15;
  const int ty = tid >> 4;

  float acc[8][4];
#pragma unroll
  for (int i = 0; i < 8; ++i)
#pragma unroll
    for (int j = 0; j < 4; ++j) acc[i][j] = 0.f;

  const int ar = tid >> 1;
  const int ak = (tid & 1) * 8;
  const float* Aptr = X + (size_t)(m0 + ar) * DIN + ak;
  const int bk = tid >> 4;
  const int bc = (tid & 15) * 4;
  const float* Bptr = Wx + (size_t)bk * GATES + n0 + bc;

  for (int k0 = 0; k0 < DIN; k0 += 16) {
    const float4 a0 = *(const float4*)(Aptr);
    const float4 a1 = *(const float4*)(Aptr + 4);
    const float4 bv = *(const float4*)(Bptr);
    Aptr += 16;
    Bptr += (size_t)16 * GATES;

    __syncthreads();
    As[ak + 0][ar] = a0.x; As[ak + 1][ar] = a0.y;
    As[ak + 2][ar] = a0.z; As[ak + 3][ar] = a0.w;
    As[ak + 4][ar] = a1.x; As[ak + 5][ar] = a1.y;
    As[ak + 6][ar] = a1.z; As[ak + 7][ar] = a1.w;
    *(float4*)&Bs[bk][bc] = bv;
    __syncthreads();

#pragma unroll
    for (int k = 0; k < 16; ++k) {
      const float4 av0 = *(const float4*)&As[k][ty * 8];
      const float4 av1 = *(const float4*)&As[k][ty * 8 + 4];
      const float4 bvv = *(const float4*)&Bs[k][tx * 4];
      const float ar8[8] = {av0.x, av0.y, av0.z, av0.w,
                            av1.x, av1.y, av1.z, av1.w};
      const float br4[4] = {bvv.x, bvv.y, bvv.z, bvv.w};
#pragma unroll
      for (int i = 0; i < 8; ++i)
#pragma unroll
        for (int j = 0; j < 4; ++j)
          acc[i][j] = fmaf(ar8[i], br4[j], acc[i][j]);
    }
  }

  float bs[4];
#pragma unroll
  for (int j = 0; j < 4; ++j) bs[j] = bias[n0 + tx * 4 + j];
#pragma unroll
  for (int i = 0; i < 8; ++i) {
    const int row = m0 + ty * 8 + i;
    ushort4 o;
    o.x = bfr(acc[i][0] + bs[0]);
    o.y = bfr(acc[i][1] + bs[1]);
    o.z = bfr(acc[i][2] + bs[2]);
    o.w = bfr(acc[i][3] + bs[3]);
    *(ushort4*)&Zl[(size_t)row * GATES + n0 + tx * 4] = o;
  }
}

/* ---------------- Phase 2: recurrence --------------------------------------
 * One block = one LSTM l x 6 sequences. group=4 -> 512 blocks = 2 blocks/CU,
 * 12 waves/CU. Thread q owns hidden unit q; 4 gate weights arrive as one
 * coalesced dwordx2 of packed bf16. Z(t+1) loads are software-pipelined
 * behind step t's k-loop. h double-buffered in LDS; c in registers. */
__global__ __launch_bounds__(384, 3) void recur(const unsigned short* __restrict__ Z,
                                                float* __restrict__ out,
                                                const uint2* __restrict__ Wh2,
                                                int lbase, int group) {
  const int bi = blockIdx.x;
  const int l_local = bi % group;       /* round-robin -> XCD L2 locality */
  const int chunk = bi / group;
  const int l = lbase + l_local;
  const uint2* __restrict__ Whl = Wh2 + (size_t)l * HID * HID;
  const unsigned short* __restrict__ Zl = Z + (size_t)l_local * NROWS * GATES;
  const int q = threadIdx.x;            /* hidden unit 0..383 */
  const int n0 = chunk * SCH;
  const bool rev = (l & 1);

  __shared__ float h_lds[2][HID * 8];   /* [buf][k*8 + s], 2 x 12 KB */

  float c[SCH];
#pragma unroll
  for (int s = 0; s < SCH; ++s) c[s] = 0.f;
#pragma unroll
  for (int s = 0; s < 8; ++s) h_lds[0][q * 8 + s] = 0.f;
  __syncthreads();

  /* feature-row r(s,t): horizontal r = n*24 + t ; vertical r = (n/24)*576 + t*24 + n%24 */
  int rbase[SCH];
  int rstep;
  if (l < 2) {
    rstep = 1;
#pragma unroll
    for (int s = 0; s < SCH; ++s) rbase[s] = (n0 + s) * SEQT;
  } else {
    rstep = 24;
#pragma unroll
    for (int s = 0; s < SCH; ++s) {
      const int n = n0 + s;
      rbase[s] = (n / 24) * 576 + (n % 24);
    }
  }

  /* Z prefetch registers: zn[gate][s] for the NEXT step */
  float zn[4][SCH];
  {
    const int t0 = rev ? (SEQT - 1) : 0;
#pragma unroll
    for (int s = 0; s < SCH; ++s) {
      const unsigned short* zrow = Zl + (size_t)(rbase[s] + t0 * rstep) * GATES;
      zn[0][s] = bup(zrow[q]);
      zn[1][s] = bup(zrow[384 + q]);
      zn[2][s] = bup(zrow[768 + q]);
      zn[3][s] = bup(zrow[1152 + q]);
    }
  }

  int cur = 0;
  for (int it = 0; it < SEQT; ++it) {
    const int tt = rev ? (SEQT - 1 - it) : it;

    float gi[SCH], gf[SCH], gc[SCH], go[SCH];
#pragma unroll
    for (int s = 0; s < SCH; ++s) {
      gi[s] = zn[0][s]; gf[s] = zn[1][s];
      gc[s] = zn[2][s]; go[s] = zn[3][s];
    }

    /* issue next step's Z loads now; consumed only next iteration, so the
     * k-loop below hides their HBM latency */
    if (it + 1 < SEQT) {
      const int tn = rev ? (SEQT - 2 - it) : (it + 1);
#pragma unroll
      for (int s = 0; s < SCH; ++s) {
        const unsigned short* zrow = Zl + (size_t)(rbase[s] + tn * rstep) * GATES;
        zn[0][s] = bup(zrow[q]);
        zn[1][s] = bup(zrow[384 + q]);
        zn[2][s] = bup(zrow[768 + q]);
        zn[3][s] = bup(zrow[1152 + q]);
      }
    }

    const uint2* wp = Whl + q;
    const float* hb = h_lds[cur];
#pragma unroll 8
    for (int k = 0; k < HID; ++k) {
      const uint2 w = wp[(size_t)k * HID];
      const float wi = __uint_as_float(w.x << 16);
      const float wf = __uint_as_float(w.x & 0xFFFF0000u);
      const float wc = __uint_as_float(w.y << 16);
      const float wo = __uint_as_float(w.y & 0xFFFF0000u);
      const float4 h0 = *(const float4*)&hb[k * 8];
      const float2 h1 = *(const float2*)&hb[k * 8 + 4];
      const float hv[SCH] = {h0.x, h0.y, h0.z, h0.w, h1.x, h1.y};
#pragma unroll
      for (int s = 0; s < SCH; ++s) {
        gi[s] = fmaf(hv[s], wi, gi[s]);
        gf[s] = fmaf(hv[s], wf, gf[s]);
        gc[s] = fmaf(hv[s], wc, gc[s]);
        go[s] = fmaf(hv[s], wo, go[s]);
      }
    }

    float* hn = h_lds[cur ^ 1];
#pragma unroll
    for (int s = 0; s < SCH; ++s) {
      const float ig = fast_sigmoid(gi[s]);
      const float fg = fast_sigmoid(gf[s]);
      const float cd = fast_tanh(gc[s]);
      const float og = fast_sigmoid(go[s]);
      const float cn = fmaf(fg, c[s], ig * cd);
      c[s] = cn;
      const float hv = og * fast_tanh(cn);
      hn[q * 8 + s] = hv;
      out[(size_t)(rbase[s] + tt * rstep) * GATES + l * HID + q] = hv;
    }
    __syncthreads();   /* new h visible before next step's GEMM reads */
    cur ^= 1;
  }
}

extern "C" void kernel_launch(void* const* d_in, const int* in_sizes, int n_in,
                              void* d_out, int out_size, void* d_ws, size_t ws_size,
                              hipStream_t stream) {
  const float* feat = (const float*)d_in[0];
  WPtrs P;
  P.Wx[0] = (const float*)d_in[1];  P.Wh[0] = (const float*)d_in[2];  P.b[0] = (const float*)d_in[3];
  P.Wx[1] = (const float*)d_in[4];  P.Wh[1] = (const float*)d_in[5];  P.b[1] = (const float*)d_in[6];
  P.Wx[2] = (const float*)d_in[7];  P.Wh[2] = (const float*)d_in[8];  P.b[2] = (const float*)d_in[9];
  P.Wx[3] = (const float*)d_in[10]; P.Wh[3] = (const float*)d_in[11]; P.b[3] = (const float*)d_in[12];
  float* out = (float*)d_out;
  unsigned short* Z = (unsigned short*)d_ws;

  const size_t slabB = (size_t)NROWS * GATES * sizeof(unsigned short); /* 56.6 MB bf16 slab */
  const size_t whB   = (size_t)4 * HID * HID * sizeof(uint2);          /* 4.72 MB packed Wh */
  const int group = (ws_size >= 4 * slabB + whB) ? 4
                  : (ws_size >= 2 * slabB + whB) ? 2 : 1;
  uint2* Wh2 = (uint2*)((char*)d_ws + (size_t)group * slabB);

  repack_wh<<<(4 * HID * HID + 255) / 256, 256, 0, stream>>>(P, Wh2);

  for (int lbase = 0; lbase < 4; lbase += group) {
    gemm_z<<<dim3(24 * group, NROWS / 128), 256, 0, stream>>>(feat, P, lbase, Z);
    recur<<<dim3((NSEQ / SCH) * group), 384, 0, stream>>>(Z, out, Wh2, lbase, group);
  }
}